// Round 5
// baseline (3201.084 us; speedup 1.0000x reference)
//
#include <hip/hip_runtime.h>

#define NN 50000
#define NE 800000
#define ND 128
#define ED 64
#define CAP 64    // per-node bucket capacity; P(deg>=64 | Poisson(16)) ~ 1e-53

// ---------------- workspace layout (element offsets, 4B elems) ----------------
// cursor int[50176]        @ 0         (zeroed; doubles as true in-degree after fill)
// cbArr  f32[50176]        @ 50176
// sArr   f32[50176]        @ 100352
// bucket int2[50176*64]    @ 150528    (byte 602,112 — 8B aligned)
// F      f32[50176*64]     @ 6573056   -> total 9,784,320 elems = 39.1 MB
// A128 (f32[NN*128]) lives in d_out: gather writes it, GEMM reads+overwrites.
// norm/invd arrays are gone: norm = rsqrtf(cursor+1) computed where needed;
// gemm reconstructs invd = cbArr - sArr.

// Bucket fill: one pass over edges, no deg/scan needed. cursor[d] counts up
// (true degree even past CAP), old value is the slot. Record {src, edge_id}.
__global__ void k_fill(const int* __restrict__ dst, const int* __restrict__ src,
                       int* __restrict__ cursor, int2* __restrict__ bucket) {
    int e = blockIdx.x * blockDim.x + threadIdx.x;
    if (e < NE) {
        int d = dst[e], s = src[e];
        int c = atomicAdd(&cursor[d], 1);
        if (c < CAP) bucket[(d << 6) + c] = make_int2(s, e);
    }
}

// One wave per dst node. cnt <= 64 by construction -> single record load per
// lane (8B coalesced) + one gathered cursor[src] dword (norm computed inline);
// inner loop broadcasts record j via shfl. Lane covers nfeat columns {2l,2l+1}
// via one dwordx2. Exact tail loop.
__global__ __launch_bounds__(256) void k_gather(
        const int2* __restrict__ bucket, const int* __restrict__ cursor,
        const float* __restrict__ nfeat, const float* __restrict__ efeat,
        float* __restrict__ A128, float* __restrict__ F,
        float* __restrict__ cbArr, float* __restrict__ sArr) {
    const int lane = threadIdx.x & 63;
    int n = blockIdx.x * 4 + (threadIdx.x >> 6);
    if (n >= NN) return;
    int rawc = cursor[n];
    int cnt = rawc > CAP ? CAP : rawc;      // safety clamp (never taken)
    float degf = (float)(rawc + 1);
    float nd = rsqrtf(degf);
    float iv = 1.0f / degf;
    float gx = 0.f, gy = 0.f, accF = 0.f;

    int2 r2 = make_int2(0, 0);
    float nsl = 0.f;                        // 0.0f for invalid lanes
    if (lane < cnt) {
        r2 = bucket[(n << 6) + lane];
        nsl = rsqrtf((float)(cursor[r2.x] + 1));   // norm[src]
    }
    float tA = nsl;

    int mf = cnt & ~7;
    for (int j = 0; j < mf; j += 8) {
#pragma unroll
        for (int u = 0; u < 8; ++u) {
            int jj = j + u;
            int s    = __shfl(r2.x, jj);
            float ns = __shfl(nsl, jj);
            int e2   = __shfl(r2.y, jj);
            float2 nf = *(const float2*)&nfeat[(size_t)s * ND + 2 * lane];
            float ef = __builtin_nontemporal_load(&efeat[(size_t)e2 * ED + lane]);
            gx   += ns * nf.x;
            gy   += ns * nf.y;
            accF += ns * ef;
        }
    }
    for (int j = mf; j < cnt; ++j) {        // exact tail
        int s    = __shfl(r2.x, j);
        float ns = __shfl(nsl, j);
        int e2   = __shfl(r2.y, j);
        float2 nf = *(const float2*)&nfeat[(size_t)s * ND + 2 * lane];
        float ef = __builtin_nontemporal_load(&efeat[(size_t)e2 * ED + lane]);
        gx   += ns * nf.x;
        gy   += ns * nf.y;
        accF += ns * ef;
    }
    // wave-reduce tA (sum of norm[src] over all incoming edges)
#pragma unroll
    for (int o = 32; o > 0; o >>= 1) tA += __shfl_xor(tA, o);

    float2 nf0 = *(const float2*)&nfeat[(size_t)n * ND + 2 * lane];
    float2 a;
    a.x = nd * gx + iv * nf0.x;
    a.y = nd * gy + iv * nf0.y;
    *(float2*)&A128[(size_t)n * ND + 2 * lane] = a;
    F[(size_t)n * ED + lane] = nd * accF;
    if (lane == 0) {
        float sA = nd * tA;                 // == sum over edges of norm[src]*norm[dst]
        cbArr[n] = sA + iv;
        sArr[n]  = sA;
    }
}

// out[n][j] = sum_{k<128} A128[n][k]*Wn[k][j] + sum_{k<64} F[n][k]*We[k][j]
//           + cb[n]*bn[j] + s[n]*be[j] + (cb[n]-s[n])*resid[j]
#define TM 64
#define KC 32

__device__ __forceinline__ void load_a(int kb, int nodeBase, int tid,
                                       const float* __restrict__ A128,
                                       const float* __restrict__ F,
                                       float4* rA) {
#pragma unroll
    for (int i = 0; i < 2; ++i) {
        int idx = tid + 256 * i;
        int node = idx >> 3;
        int kl = (idx & 7) * 4;
        int gn = nodeBase + node;
        float4 v = make_float4(0.f, 0.f, 0.f, 0.f);
        if (gn < NN) {
            v = (kb < 4) ? *(const float4*)&A128[(size_t)gn * ND + kb * 32 + kl]
                         : *(const float4*)&F[(size_t)gn * ED + (kb - 4) * 32 + kl];
        }
        rA[i] = v;
    }
}

__device__ __forceinline__ void load_b(int kb, int tid,
                                       const float* __restrict__ Wn,
                                       const float* __restrict__ We,
                                       float4* rB) {
#pragma unroll
    for (int i = 0; i < 4; ++i) {
        int idx = tid + 256 * i;
        int kl = idx >> 5;
        int j = (idx & 31) * 4;
        int k = kb * 32 + kl;
        rB[i] = (k < ND) ? *(const float4*)&Wn[(size_t)k * ND + j]
                         : *(const float4*)&We[(size_t)(k - ND) * ND + j];
    }
}

__global__ __launch_bounds__(256) void k_gemm(
        const float* __restrict__ Wn, const float* __restrict__ bn,
        const float* __restrict__ We, const float* __restrict__ be,
        const float* __restrict__ resid,
        const float* __restrict__ cbArr, const float* __restrict__ sArr,
        const float* __restrict__ F, const float* A128, float* out) {
    __shared__ float As[KC][TM + 4];
    __shared__ float Bs[KC][ND + 4];

    const int tid = threadIdx.x;
    const int nodeBase = blockIdx.x * TM;

    const int wv = tid >> 6, lane = tid & 63;
    const int wm = wv & 1, wn = wv >> 1;
    const int ln = lane & 7, lj = lane >> 3;
    const int rowN = wm * 32 + ln * 4;
    const int colJ = wn * 64 + lj * 8;

    float acc[4][8];
#pragma unroll
    for (int r = 0; r < 4; ++r)
#pragma unroll
        for (int c = 0; c < 8; ++c) acc[r][c] = 0.0f;

    // register double-buffer: kb's tile is in rA/rB when the loop body starts
    float4 rA[2], rB[4];
    load_a(0, nodeBase, tid, A128, F, rA);
    load_b(0, tid, Wn, We, rB);

#pragma unroll
    for (int kb = 0; kb < 6; ++kb) {
        __syncthreads();                    // previous compute done reading LDS
#pragma unroll
        for (int i = 0; i < 2; ++i) {
            int idx = tid + 256 * i;
            int node = idx >> 3;
            int kl = (idx & 7) * 4;
            As[kl + 0][node] = rA[i].x;
            As[kl + 1][node] = rA[i].y;
            As[kl + 2][node] = rA[i].z;
            As[kl + 3][node] = rA[i].w;
        }
#pragma unroll
        for (int i = 0; i < 4; ++i) {
            int idx = tid + 256 * i;
            int kl = idx >> 5;
            int j = (idx & 31) * 4;
            *(float4*)&Bs[kl][j] = rB[i];
        }
        __syncthreads();

        // prefetch next k-step while computing this one (hides global latency)
        float4 nA[2], nB[4];
        if (kb < 5) {
            load_a(kb + 1, nodeBase, tid, A128, F, nA);
            load_b(kb + 1, tid, Wn, We, nB);
        }

#pragma unroll
        for (int kl = 0; kl < KC; ++kl) {
            float4 a4 = *(const float4*)&As[kl][rowN];
            float4 b0 = *(const float4*)&Bs[kl][colJ];
            float4 b1 = *(const float4*)&Bs[kl][colJ + 4];
            float av[4] = {a4.x, a4.y, a4.z, a4.w};
            float bv[8] = {b0.x, b0.y, b0.z, b0.w, b1.x, b1.y, b1.z, b1.w};
#pragma unroll
            for (int r = 0; r < 4; ++r)
#pragma unroll
                for (int c = 0; c < 8; ++c) acc[r][c] += av[r] * bv[c];
        }

        if (kb < 5) {
#pragma unroll
            for (int i = 0; i < 2; ++i) rA[i] = nA[i];
#pragma unroll
            for (int i = 0; i < 4; ++i) rB[i] = nB[i];
        }
    }

#pragma unroll
    for (int r = 0; r < 4; ++r) {
        int gn = nodeBase + rowN + r;
        if (gn >= NN) continue;
        float cb = cbArr[gn], sv = sArr[gn];
        float iv = cb - sv;                 // == invd[gn] (reconstructed)
        float o[8];
#pragma unroll
        for (int c = 0; c < 8; ++c) {
            int j = colJ + c;
            o[c] = acc[r][c] + cb * bn[j] + sv * be[j] + iv * resid[j];
        }
        float4* op = (float4*)&out[(size_t)gn * ND + colJ];
        op[0] = make_float4(o[0], o[1], o[2], o[3]);
        op[1] = make_float4(o[4], o[5], o[6], o[7]);
    }
}

extern "C" void kernel_launch(void* const* d_in, const int* in_sizes, int n_in,
                              void* d_out, int out_size, void* d_ws, size_t ws_size,
                              hipStream_t stream) {
    const int*   src   = (const int*)  d_in[0];
    const int*   dst   = (const int*)  d_in[1];
    const float* nfeat = (const float*)d_in[2];
    const float* efeat = (const float*)d_in[3];
    const float* Wn    = (const float*)d_in[4];
    const float* bn    = (const float*)d_in[5];
    const float* We    = (const float*)d_in[6];
    const float* be    = (const float*)d_in[7];
    const float* resid = (const float*)d_in[8];
    float* out = (float*)d_out;
    float* ws  = (float*)d_ws;

    int*   cursor = (int*)d_ws;
    float* cbArr  = ws + 50176;
    float* sArr   = ws + 100352;
    int2*  bucket = (int2*)((int*)d_ws + 150528);
    float* F      = ws + 6573056;
    float* A128   = out;   // gather writes A into d_out; gemm reads + overwrites

    // zero cursor only (200 KB)
    hipMemsetAsync(d_ws, 0, (size_t)50176 * 4, stream);

    k_fill  <<<(NE + 255) / 256, 256, 0, stream>>>(dst, src, cursor, bucket);
    k_gather<<<12500, 256, 0, stream>>>(bucket, cursor, nfeat, efeat,
                                        A128, F, cbArr, sArr);
    k_gemm  <<<(NN + TM - 1) / TM, 256, 0, stream>>>(Wn, bn, We, be, resid,
                                                     cbArr, sArr, F, A128, out);
}

// Round 6
// 444.736 us; speedup vs baseline: 7.1977x; 7.1977x over previous
//
#include <hip/hip_runtime.h>

#define NN 50000
#define NE 800000
#define ND 128
#define ED 64
#define CAP 64    // per-node bucket capacity; P(deg>=64 | Poisson(16)) ~ 1e-53

// ---------------- workspace layout (element offsets, 4B elems) ----------------
// cursor int[50176]        @ 0         (zeroed; doubles as true in-degree after fill)
// cbArr  f32[50176]        @ 50176
// sArr   f32[50176]        @ 100352
// bucket int2[50176*64]    @ 150528    (byte 602,112 — 8B aligned)
// F      f32[50176*64]     @ 6573056   -> total 9,784,320 elems = 39.1 MB
// A128 (f32[NN*128]) lives in d_out: gather writes it, GEMM reads+overwrites.
// norm/invd arrays are gone: norm = rsqrtf(cursor+1) computed where needed;
// gemm reconstructs invd = cbArr - sArr.

// Bucket fill: one pass over edges, no deg/scan needed. cursor[d] counts up
// (true degree even past CAP), old value is the slot. Record {src, edge_id}.
__global__ void k_fill(const int* __restrict__ dst, const int* __restrict__ src,
                       int* __restrict__ cursor, int2* __restrict__ bucket) {
    int e = blockIdx.x * blockDim.x + threadIdx.x;
    if (e < NE) {
        int d = dst[e], s = src[e];
        int c = atomicAdd(&cursor[d], 1);
        if (c < CAP) bucket[(d << 6) + c] = make_int2(s, e);
    }
}

// One wave per dst node. cnt <= 64 by construction -> single record load per
// lane (8B coalesced) + one gathered cursor[src] dword (norm computed inline);
// inner loop broadcasts record j via shfl. Lane covers nfeat columns {2l,2l+1}
// via one dwordx2. Exact tail loop.
__global__ __launch_bounds__(256) void k_gather(
        const int2* __restrict__ bucket, const int* __restrict__ cursor,
        const float* __restrict__ nfeat, const float* __restrict__ efeat,
        float* __restrict__ A128, float* __restrict__ F,
        float* __restrict__ cbArr, float* __restrict__ sArr) {
    const int lane = threadIdx.x & 63;
    int n = blockIdx.x * 4 + (threadIdx.x >> 6);
    if (n >= NN) return;
    int rawc = cursor[n];
    int cnt = rawc > CAP ? CAP : rawc;      // safety clamp (never taken)
    float degf = (float)(rawc + 1);
    float nd = rsqrtf(degf);
    float iv = 1.0f / degf;
    float gx = 0.f, gy = 0.f, accF = 0.f;

    int2 r2 = make_int2(0, 0);
    float nsl = 0.f;                        // 0.0f for invalid lanes
    if (lane < cnt) {
        r2 = bucket[(n << 6) + lane];
        nsl = rsqrtf((float)(cursor[r2.x] + 1));   // norm[src]
    }
    float tA = nsl;

    int mf = cnt & ~7;
    for (int j = 0; j < mf; j += 8) {
#pragma unroll
        for (int u = 0; u < 8; ++u) {
            int jj = j + u;
            int s    = __shfl(r2.x, jj);
            float ns = __shfl(nsl, jj);
            int e2   = __shfl(r2.y, jj);
            float2 nf = *(const float2*)&nfeat[(size_t)s * ND + 2 * lane];
            float ef = __builtin_nontemporal_load(&efeat[(size_t)e2 * ED + lane]);
            gx   += ns * nf.x;
            gy   += ns * nf.y;
            accF += ns * ef;
        }
    }
    for (int j = mf; j < cnt; ++j) {        // exact tail
        int s    = __shfl(r2.x, j);
        float ns = __shfl(nsl, j);
        int e2   = __shfl(r2.y, j);
        float2 nf = *(const float2*)&nfeat[(size_t)s * ND + 2 * lane];
        float ef = __builtin_nontemporal_load(&efeat[(size_t)e2 * ED + lane]);
        gx   += ns * nf.x;
        gy   += ns * nf.y;
        accF += ns * ef;
    }
    // wave-reduce tA (sum of norm[src] over all incoming edges)
#pragma unroll
    for (int o = 32; o > 0; o >>= 1) tA += __shfl_xor(tA, o);

    float2 nf0 = *(const float2*)&nfeat[(size_t)n * ND + 2 * lane];
    float2 a;
    a.x = nd * gx + iv * nf0.x;
    a.y = nd * gy + iv * nf0.y;
    *(float2*)&A128[(size_t)n * ND + 2 * lane] = a;
    F[(size_t)n * ED + lane] = nd * accF;
    if (lane == 0) {
        float sA = nd * tA;                 // == sum over edges of norm[src]*norm[dst]
        cbArr[n] = sA + iv;
        sArr[n]  = sA;
    }
}

// out[n][j] = sum_{k<128} A128[n][k]*Wn[k][j] + sum_{k<64} F[n][k]*We[k][j]
//           + cb[n]*bn[j] + s[n]*be[j] + (cb[n]-s[n])*resid[j]
#define TM 64
#define KC 32

__global__ __launch_bounds__(256) void k_gemm(
        const float* __restrict__ Wn, const float* __restrict__ bn,
        const float* __restrict__ We, const float* __restrict__ be,
        const float* __restrict__ resid,
        const float* __restrict__ cbArr, const float* __restrict__ sArr,
        const float* __restrict__ F, const float* A128, float* out) {
    __shared__ float As[KC][TM + 4];
    __shared__ float Bs[KC][ND + 4];

    const int tid = threadIdx.x;
    const int nodeBase = blockIdx.x * TM;

    const int wv = tid >> 6, lane = tid & 63;
    const int wm = wv & 1, wn = wv >> 1;
    const int ln = lane & 7, lj = lane >> 3;
    const int rowN = wm * 32 + ln * 4;
    const int colJ = wn * 64 + lj * 8;

    float acc[4][8];
#pragma unroll
    for (int r = 0; r < 4; ++r)
#pragma unroll
        for (int c = 0; c < 8; ++c) acc[r][c] = 0.0f;

#pragma unroll 1   // pin: do NOT unroll k-loop (round-5 full-unroll spilled to scratch)
    for (int kb = 0; kb < 6; ++kb) {
        __syncthreads();
#pragma unroll
        for (int i = 0; i < 2; ++i) {
            int idx = tid + 256 * i;
            int node = idx >> 3;
            int kl = (idx & 7) * 4;
            int gn = nodeBase + node;
            float ax = 0.f, ay = 0.f, az = 0.f, aw = 0.f;
            if (gn < NN) {
                if (kb < 4) {
                    float4 g4 = *(const float4*)&A128[(size_t)gn * ND + kb * 32 + kl];
                    ax = g4.x; ay = g4.y; az = g4.z; aw = g4.w;
                } else {
                    float4 f4 = *(const float4*)&F[(size_t)gn * ED + (kb - 4) * 32 + kl];
                    ax = f4.x; ay = f4.y; az = f4.z; aw = f4.w;
                }
            }
            As[kl + 0][node] = ax;
            As[kl + 1][node] = ay;
            As[kl + 2][node] = az;
            As[kl + 3][node] = aw;
        }
#pragma unroll
        for (int i = 0; i < 4; ++i) {
            int idx = tid + 256 * i;
            int kl = idx >> 5;
            int j = (idx & 31) * 4;
            int k = kb * 32 + kl;
            float4 b4 = (k < ND) ? *(const float4*)&Wn[(size_t)k * ND + j]
                                 : *(const float4*)&We[(size_t)(k - ND) * ND + j];
            *(float4*)&Bs[kl][j] = b4;
        }
        __syncthreads();
#pragma unroll
        for (int kl = 0; kl < KC; ++kl) {
            float4 a4 = *(const float4*)&As[kl][rowN];
            float4 b0 = *(const float4*)&Bs[kl][colJ];
            float4 b1 = *(const float4*)&Bs[kl][colJ + 4];
            float av[4] = {a4.x, a4.y, a4.z, a4.w};
            float bv[8] = {b0.x, b0.y, b0.z, b0.w, b1.x, b1.y, b1.z, b1.w};
#pragma unroll
            for (int r = 0; r < 4; ++r)
#pragma unroll
                for (int c = 0; c < 8; ++c) acc[r][c] += av[r] * bv[c];
        }
    }

#pragma unroll
    for (int r = 0; r < 4; ++r) {
        int gn = nodeBase + rowN + r;
        if (gn >= NN) continue;
        float cb = cbArr[gn], sv = sArr[gn];
        float iv = cb - sv;                 // == invd[gn] (reconstructed)
        float o[8];
#pragma unroll
        for (int c = 0; c < 8; ++c) {
            int j = colJ + c;
            o[c] = acc[r][c] + cb * bn[j] + sv * be[j] + iv * resid[j];
        }
        float4* op = (float4*)&out[(size_t)gn * ND + colJ];
        op[0] = make_float4(o[0], o[1], o[2], o[3]);
        op[1] = make_float4(o[4], o[5], o[6], o[7]);
    }
}

extern "C" void kernel_launch(void* const* d_in, const int* in_sizes, int n_in,
                              void* d_out, int out_size, void* d_ws, size_t ws_size,
                              hipStream_t stream) {
    const int*   src   = (const int*)  d_in[0];
    const int*   dst   = (const int*)  d_in[1];
    const float* nfeat = (const float*)d_in[2];
    const float* efeat = (const float*)d_in[3];
    const float* Wn    = (const float*)d_in[4];
    const float* bn    = (const float*)d_in[5];
    const float* We    = (const float*)d_in[6];
    const float* be    = (const float*)d_in[7];
    const float* resid = (const float*)d_in[8];
    float* out = (float*)d_out;
    float* ws  = (float*)d_ws;

    int*   cursor = (int*)d_ws;
    float* cbArr  = ws + 50176;
    float* sArr   = ws + 100352;
    int2*  bucket = (int2*)((int*)d_ws + 150528);
    float* F      = ws + 6573056;
    float* A128   = out;   // gather writes A into d_out; gemm reads + overwrites

    // zero cursor only (200 KB)
    hipMemsetAsync(d_ws, 0, (size_t)50176 * 4, stream);

    k_fill  <<<(NE + 255) / 256, 256, 0, stream>>>(dst, src, cursor, bucket);
    k_gather<<<12500, 256, 0, stream>>>(bucket, cursor, nfeat, efeat,
                                        A128, F, cbArr, sArr);
    k_gemm  <<<(NN + TM - 1) / TM, 256, 0, stream>>>(Wn, bn, We, be, resid,
                                                     cbArr, sArr, F, A128, out);
}